// Round 3
// baseline (806.891 us; speedup 1.0000x reference)
//
#include <hip/hip_runtime.h>
#include <stdint.h>

#define MDIM 4096
#define NDIM 4096
#define KDIM 4096
#define NBINS 2048        // 2 rows per bin
#define RPB 2             // rows per bin

typedef float f32x4 __attribute__((ext_vector_type(4)));
typedef __bf16 bf16x8 __attribute__((ext_vector_type(8)));
typedef short s16x8 __attribute__((ext_vector_type(8)));

__device__ __forceinline__ unsigned short f2bf(float x) {
  union { float f; unsigned u; } v; v.f = x;
  return (unsigned short)((v.u + 0x7fffu + ((v.u >> 16) & 1u)) >> 16);
}

// ---- 1a. histogram of rows into 2048 bins (fire-and-forget atomics) ----
__global__ void hist_kernel(const int* __restrict__ rows, int nnz, int* __restrict__ binCnt) {
  int i = blockIdx.x * blockDim.x + threadIdx.x;
  int stride = gridDim.x * blockDim.x;
  for (; i < nnz; i += stride) atomicAdd(&binCnt[rows[i] >> 1], 1);
}

// ---- 1b. exclusive prefix over 2048 bins (single block, 1024 threads) ----
__global__ void prefix_kernel(const int* __restrict__ binCnt, int* __restrict__ binOfs,
                              int* __restrict__ binCursor) {
  __shared__ int c[1024];
  int t = threadIdx.x;
  int r0 = binCnt[2 * t], r1 = binCnt[2 * t + 1];
  c[t] = r0 + r1;
  __syncthreads();
  for (int off = 1; off < 1024; off <<= 1) {
    int v = (t >= off) ? c[t - off] : 0;
    __syncthreads();
    c[t] += v;
    __syncthreads();
  }
  int e0 = (t == 0) ? 0 : c[t - 1];
  binOfs[2 * t] = e0;      binCursor[2 * t] = e0;
  binOfs[2 * t + 1] = e0 + r0; binCursor[2 * t + 1] = e0 + r0;
  if (t == 1023) binOfs[2048] = c[1023];
}

// ---- 1c. scatter-sort nnz into bin-contiguous order ----
__global__ void sort_kernel(const int* __restrict__ rows, const int* __restrict__ cols,
                            const float* __restrict__ vals, int nnz,
                            int* __restrict__ binCursor, int* __restrict__ sRC,
                            float* __restrict__ sV) {
  int i = blockIdx.x * blockDim.x + threadIdx.x;
  if (i >= nnz) return;
  int r = rows[i];
  int pos = atomicAdd(&binCursor[r >> 1], 1);
  sRC[pos] = ((r & 1) << 12) | cols[i];
  sV[pos] = vals[i];
}

// ---- 1d. per-bin LDS fp32 accumulate + dense bf16 writeout (no memset of W) ----
__global__ __launch_bounds__(256) void binacc_kernel(const int* __restrict__ binOfs,
                                                     const int* __restrict__ sRC,
                                                     const float* __restrict__ sV,
                                                     short* __restrict__ Wb) {
  __shared__ float acc[RPB * 4096];  // 32 KB
  int b = blockIdx.x, tid = threadIdx.x;
  for (int j = tid; j < RPB * 4096; j += 256) acc[j] = 0.f;
  __syncthreads();
  int s = binOfs[b], e = binOfs[b + 1];
  for (int i = s + tid; i < e; i += 256) {
    int rc = sRC[i];
    atomicAdd(&acc[((rc >> 12) << 12) | (rc & 4095)], sV[i]);
  }
  __syncthreads();
  for (int j = tid * 8; j < RPB * 4096; j += 256 * 8) {
    s16x8 v;
#pragma unroll
    for (int q = 0; q < 8; q++) v[q] = (short)f2bf(acc[j + q]);
    *(s16x8*)&Wb[(size_t)b * (RPB * 4096) + j] = v;
  }
}

// ---- 2. transpose+convert x (K x N fp32) -> xT (N x K bf16, k-contiguous) ----
__global__ void transx_kernel(const float* __restrict__ x, short* __restrict__ xT) {
  __shared__ float tile[32][33];
  int n0 = blockIdx.x * 32, k0 = blockIdx.y * 32;
  int tx = threadIdx.x, ty = threadIdx.y;  // block (32, 8)
#pragma unroll
  for (int j = 0; j < 32; j += 8)
    tile[ty + j][tx] = x[(k0 + ty + j) * NDIM + n0 + tx];
  __syncthreads();
#pragma unroll
  for (int j = 0; j < 32; j += 8)
    xT[(n0 + ty + j) * KDIM + k0 + tx] = (short)f2bf(tile[tx][ty + j]);
}

// ---- 3. bf16 MFMA GEMM, double-buffered LDS, raw barriers + fine vmcnt ----
// 128x128 tile, BK=32, 4 waves x (64x64 = 4x4 of 16x16x32). Per iter each wave
// prefetches 4 x 1KB fragments (2 A + 2 B) of tile k+1 into the idle buffer,
// then waits vmcnt(4) (= previous iter's loads) -- never vmcnt(0) in-loop.
__global__ __launch_bounds__(256) void gemm_kernel(const short* __restrict__ A,
                                                   const short* __restrict__ Bt,
                                                   const float* __restrict__ bias,
                                                   float* __restrict__ C) {
  __shared__ __align__(16) short sA[2][128 * 32];
  __shared__ __align__(16) short sB[2][128 * 32];
  int tid = threadIdx.x, lane = tid & 63, wave = tid >> 6;
  int wr = wave >> 1, wc = wave & 1;
  int m16 = lane & 15, quad = lane >> 4;
  int rowBase = blockIdx.y * 128, colBase = blockIdx.x * 128;

  f32x4 acc[4][4];
#pragma unroll
  for (int i = 0; i < 4; i++)
#pragma unroll
    for (int j = 0; j < 4; j++) acc[i][j] = f32x4{0.f, 0.f, 0.f, 0.f};

  // Fragment f (16 rows x 32 k) = 64 chunks of 16B, chunk=lane:
  // row = f*16 + (lane&15), k = (lane>>4)*8. Wave stages f = wave, wave+4.
  const short* aSrc[2];
  const short* bSrc[2];
  int ldsDst[2];
#pragma unroll
  for (int s = 0; s < 2; s++) {
    int f = wave + s * 4;
    aSrc[s] = A + (size_t)(rowBase + f * 16 + m16) * KDIM + quad * 8;
    bSrc[s] = Bt + (size_t)(colBase + f * 16 + m16) * KDIM + quad * 8;
    ldsDst[s] = f * 512;  // shorts (1 KB per fragment)
  }

  // prologue: stage k=0 into buffer 0
#pragma unroll
  for (int s = 0; s < 2; s++) {
    __builtin_amdgcn_global_load_lds(
        (const __attribute__((address_space(1))) void*)aSrc[s],
        (__attribute__((address_space(3))) void*)&sA[0][ldsDst[s]], 16, 0, 0);
    __builtin_amdgcn_global_load_lds(
        (const __attribute__((address_space(1))) void*)bSrc[s],
        (__attribute__((address_space(3))) void*)&sB[0][ldsDst[s]], 16, 0, 0);
  }

#pragma unroll 2
  for (int it = 0; it < 128; it++) {
    int buf = it & 1, nxt = buf ^ 1;
    int knext = ((it + 1) * 32) & (KDIM - 1);  // last iter wraps to 0 (harmless)
#pragma unroll
    for (int s = 0; s < 2; s++) {
      __builtin_amdgcn_global_load_lds(
          (const __attribute__((address_space(1))) void*)(aSrc[s] + knext),
          (__attribute__((address_space(3))) void*)&sA[nxt][ldsDst[s]], 16, 0, 0);
      __builtin_amdgcn_global_load_lds(
          (const __attribute__((address_space(1))) void*)(bSrc[s] + knext),
          (__attribute__((address_space(3))) void*)&sB[nxt][ldsDst[s]], 16, 0, 0);
    }
    __builtin_amdgcn_s_waitcnt(0x0F74);  // vmcnt(4): prev iter's 4 loads landed
    __builtin_amdgcn_s_barrier();

    bf16x8 a[4], b[4];
#pragma unroll
    for (int i = 0; i < 4; i++)
      a[i] = *(const bf16x8*)&sA[buf][((wr * 4 + i) * 64 + lane) * 8];
#pragma unroll
    for (int j = 0; j < 4; j++)
      b[j] = *(const bf16x8*)&sB[buf][((wc * 4 + j) * 64 + lane) * 8];
#pragma unroll
    for (int i = 0; i < 4; i++)
#pragma unroll
      for (int j = 0; j < 4; j++)
        acc[i][j] = __builtin_amdgcn_mfma_f32_16x16x32_bf16(a[i], b[j], acc[i][j], 0, 0, 0);

    __builtin_amdgcn_s_waitcnt(0xC07F);  // lgkmcnt(0): ds_reads retired
    __builtin_amdgcn_s_barrier();        // cur buffer free for next prefetch
  }
  __builtin_amdgcn_s_waitcnt(0x0F70);  // vmcnt(0): drain wrap prefetch before exit

  // Epilogue: C/D layout col = lane&15, row = quad*4 + reg
#pragma unroll
  for (int j = 0; j < 4; j++) {
    int col = colBase + wc * 64 + j * 16 + m16;
    float bv = bias[col];
#pragma unroll
    for (int i = 0; i < 4; i++) {
      int row0 = rowBase + wr * 64 + i * 16 + quad * 4;
      f32x4 v = acc[i][j];
#pragma unroll
      for (int r = 0; r < 4; r++) C[(row0 + r) * NDIM + col] = v[r] + bv;
    }
  }
}

extern "C" void kernel_launch(void* const* d_in, const int* in_sizes, int n_in,
                              void* d_out, int out_size, void* d_ws, size_t ws_size,
                              hipStream_t stream) {
  const float* x = (const float*)d_in[0];
  const int* rows = (const int*)d_in[1];
  const int* cols = (const int*)d_in[2];
  const float* vals = (const float*)d_in[3];
  const float* bias = (const float*)d_in[4];
  int nnz = in_sizes[1];
  float* y = (float*)d_out;

  // ws: [0,32MB) Wb; [32,64MB) xT; [64MB) sRC (nnz*4); [72MB) sV (nnz*4); [80MB) counters
  char* ws = (char*)d_ws;
  short* Wb = (short*)ws;
  short* xT = (short*)(ws + (32u << 20));
  int* sRC = (int*)(ws + (64u << 20));
  float* sV = (float*)(ws + (72u << 20));
  int* binCnt = (int*)(ws + (80u << 20));
  int* binOfs = binCnt + NBINS;        // NBINS+1 ints
  int* binCursor = binOfs + NBINS + 1;

  hipMemsetAsync(binCnt, 0, NBINS * sizeof(int), stream);
  hist_kernel<<<256, 256, 0, stream>>>(rows, nnz, binCnt);
  prefix_kernel<<<1, 1024, 0, stream>>>(binCnt, binOfs, binCursor);
  sort_kernel<<<(nnz + 255) / 256, 256, 0, stream>>>(rows, cols, vals, nnz, binCursor, sRC, sV);
  binacc_kernel<<<NBINS, 256, 0, stream>>>(binOfs, sRC, sV, Wb);
  transx_kernel<<<dim3(NDIM / 32, KDIM / 32), dim3(32, 8), 0, stream>>>(x, xT);
  gemm_kernel<<<dim3(NDIM / 128, MDIM / 128), 256, 0, stream>>>(Wb, xT, bias, y);
}

// Round 4
// 381.256 us; speedup vs baseline: 2.1164x; 2.1164x over previous
//
#include <hip/hip_runtime.h>
#include <stdint.h>

#define MDIM 4096
#define NDIM 4096
#define KDIM 4096

typedef float f32x4 __attribute__((ext_vector_type(4)));
typedef __bf16 bf16x8 __attribute__((ext_vector_type(8)));
typedef short s16x8 __attribute__((ext_vector_type(8)));

// Packed fragment-order layout for a 4096x4096 bf16 operand P[row][k]:
//   band b = row>>7, ktile t = k>>5, frag f = (row&127)>>4,
//   lane = ((k>>3)&3)*16 + (row&15), j = k&7
//   short index = ((((b*128 + t)*8 + f)*64) + lane)*8 + j
// One (b,t) panel = 8KB, one frag = 1KB contiguous => wave reads are
// perfectly contiguous in both global (lane*16B) and LDS.

__device__ __forceinline__ unsigned short f2bf(float x) {
  union { float f; unsigned u; } v; v.f = x;
  return (unsigned short)((v.u + 0x7fffu + ((v.u >> 16) & 1u)) >> 16);
}
__device__ __forceinline__ float bf2f(unsigned short b) {
  union { unsigned u; float f; } v; v.u = ((unsigned)b) << 16;
  return v.f;
}

// ---- 1. scatter COO directly into PACKED bf16 W (CAS accumulate) ----
__global__ void scatter_kernel(const int* __restrict__ rows, const int* __restrict__ cols,
                               const float* __restrict__ vals, unsigned* __restrict__ Wb,
                               int nnz) {
  int i = blockIdx.x * blockDim.x + threadIdx.x;
  if (i >= nnz) return;
  int m = rows[i], k = cols[i];
  float v = vals[i];
  size_t chunk = ((((size_t)(m >> 7) * 128 + (k >> 5)) * 8 + ((m >> 4) & 7)) * 64) +
                 (((k >> 3) & 3) * 16 + (m & 15));
  size_t idx = chunk * 8 + (k & 7);
  unsigned* word = &Wb[idx >> 1];
  unsigned shift = (idx & 1) ? 16u : 0u;
  unsigned old = *word, assumed;
  do {
    assumed = old;
    unsigned short cur = (unsigned short)(assumed >> shift);
    unsigned short upd = f2bf(bf2f(cur) + v);
    unsigned next = (assumed & ~(0xffffu << shift)) | ((unsigned)upd << shift);
    if (next == assumed) break;
    old = atomicCAS(word, assumed, next);
  } while (old != assumed);
}

// ---- 2. transpose+convert x (K x N fp32) -> packed bf16 B[n][k] ----
// Block: 256 threads, tile n=64 x k=32. Writes land as 4 contiguous 1KB runs.
__global__ __launch_bounds__(256) void packx_kernel(const float* __restrict__ x,
                                                    short* __restrict__ Bpk) {
  __shared__ float tile[32 * 65];  // [kk][nn], stride 65 (2-way max on read: free)
  int tid = threadIdx.x;
  int n0 = blockIdx.x * 64, k0 = blockIdx.y * 32;
#pragma unroll
  for (int r = 0; r < 8; r++) {
    int elem = r * 256 + tid;
    int kk = elem >> 6, nn = elem & 63;
    tile[kk * 65 + nn] = x[(size_t)(k0 + kk) * NDIM + n0 + nn];
  }
  __syncthreads();
  int region = tid >> 6, lane = tid & 63;
  int kh = lane >> 4, nl = region * 16 + (lane & 15);
  s16x8 v;
#pragma unroll
  for (int j = 0; j < 8; j++) v[j] = (short)f2bf(tile[(kh * 8 + j) * 65 + nl]);
  int f = ((n0 & 127) >> 4) + region;
  size_t chunk = (((size_t)(n0 >> 7) * 128 + (k0 >> 5)) * 8 + f) * 64 + lane;
  *(s16x8*)&Bpk[chunk * 8] = v;
}

// ---- 3. bf16 MFMA GEMM on packed operands, double-buffered LDS ----
// 128x128 tile, BK=32, 4 waves x (64x64 = 4x4 of 16x16x32 MFMA).
__global__ __launch_bounds__(256) void gemm_kernel(const short* __restrict__ A,
                                                   const short* __restrict__ Bt,
                                                   const float* __restrict__ bias,
                                                   float* __restrict__ C) {
  __shared__ __align__(16) short sA[2][128 * 32];
  __shared__ __align__(16) short sB[2][128 * 32];
  int tid = threadIdx.x, lane = tid & 63, wave = tid >> 6;
  int wr = wave >> 1, wc = wave & 1;
  int m16 = lane & 15, quad = lane >> 4;
  int rowBase = blockIdx.y * 128, colBase = blockIdx.x * 128;

  f32x4 acc[4][4];
#pragma unroll
  for (int i = 0; i < 4; i++)
#pragma unroll
    for (int j = 0; j < 4; j++) acc[i][j] = f32x4{0.f, 0.f, 0.f, 0.f};

  // Wave stages frags f = wave, wave+4. Global src is contiguous 1KB:
  // base + lane*16B; advances 4096 shorts (8KB) per ktile.
  const short* aSrc[2];
  const short* bSrc[2];
  int ldsDst[2];
#pragma unroll
  for (int s = 0; s < 2; s++) {
    int f = wave + s * 4;
    aSrc[s] = A + ((size_t)blockIdx.y * 128 * 8 + f) * 512 + lane * 8;
    bSrc[s] = Bt + ((size_t)blockIdx.x * 128 * 8 + f) * 512 + lane * 8;
    ldsDst[s] = f * 512;
  }

#pragma unroll
  for (int s = 0; s < 2; s++) {
    __builtin_amdgcn_global_load_lds(
        (const __attribute__((address_space(1))) void*)aSrc[s],
        (__attribute__((address_space(3))) void*)&sA[0][ldsDst[s]], 16, 0, 0);
    __builtin_amdgcn_global_load_lds(
        (const __attribute__((address_space(1))) void*)bSrc[s],
        (__attribute__((address_space(3))) void*)&sB[0][ldsDst[s]], 16, 0, 0);
  }

#pragma unroll 2
  for (int it = 0; it < 128; it++) {
    int buf = it & 1, nxt = buf ^ 1;
    int tnext = (it + 1) & 127;  // wrap prefetch stays in-bounds
#pragma unroll
    for (int s = 0; s < 2; s++) {
      __builtin_amdgcn_global_load_lds(
          (const __attribute__((address_space(1))) void*)(aSrc[s] + (size_t)tnext * 4096),
          (__attribute__((address_space(3))) void*)&sA[nxt][ldsDst[s]], 16, 0, 0);
      __builtin_amdgcn_global_load_lds(
          (const __attribute__((address_space(1))) void*)(bSrc[s] + (size_t)tnext * 4096),
          (__attribute__((address_space(3))) void*)&sB[nxt][ldsDst[s]], 16, 0, 0);
    }
    __builtin_amdgcn_s_waitcnt(0x0F74);  // vmcnt(4): prev iter's loads landed
    __builtin_amdgcn_s_barrier();

    bf16x8 a[4], b[4];
#pragma unroll
    for (int i = 0; i < 4; i++)
      a[i] = *(const bf16x8*)&sA[buf][((wr * 4 + i) * 64 + lane) * 8];
#pragma unroll
    for (int j = 0; j < 4; j++)
      b[j] = *(const bf16x8*)&sB[buf][((wc * 4 + j) * 64 + lane) * 8];
#pragma unroll
    for (int i = 0; i < 4; i++)
#pragma unroll
      for (int j = 0; j < 4; j++)
        acc[i][j] = __builtin_amdgcn_mfma_f32_16x16x32_bf16(a[i], b[j], acc[i][j], 0, 0, 0);

    __builtin_amdgcn_s_waitcnt(0xC07F);  // lgkmcnt(0): ds_reads retired
    __builtin_amdgcn_s_barrier();
  }
  __builtin_amdgcn_s_waitcnt(0x0F70);  // vmcnt(0): drain wrap prefetch

  // Epilogue: C/D layout col = lane&15, row = quad*4 + reg
#pragma unroll
  for (int j = 0; j < 4; j++) {
    int col = colBase + wc * 64 + j * 16 + m16;
    float bv = bias[col];
#pragma unroll
    for (int i = 0; i < 4; i++) {
      int row0 = rowBase + wr * 64 + i * 16 + quad * 4;
      f32x4 v = acc[i][j];
#pragma unroll
      for (int r = 0; r < 4; r++) C[(size_t)(row0 + r) * NDIM + col] = v[r] + bv;
    }
  }
}

extern "C" void kernel_launch(void* const* d_in, const int* in_sizes, int n_in,
                              void* d_out, int out_size, void* d_ws, size_t ws_size,
                              hipStream_t stream) {
  const float* x = (const float*)d_in[0];
  const int* rows = (const int*)d_in[1];
  const int* cols = (const int*)d_in[2];
  const float* vals = (const float*)d_in[3];
  const float* bias = (const float*)d_in[4];
  int nnz = in_sizes[1];
  float* y = (float*)d_out;

  // ws: [0,32MB) W packed bf16; [32,64MB) x packed bf16
  char* ws = (char*)d_ws;
  short* Wpk = (short*)ws;
  short* Xpk = (short*)(ws + (32u << 20));

  hipMemsetAsync(Wpk, 0, (size_t)MDIM * KDIM * sizeof(short), stream);
  scatter_kernel<<<(nnz + 255) / 256, 256, 0, stream>>>(rows, cols, vals, (unsigned*)Wpk, nnz);
  packx_kernel<<<dim3(NDIM / 64, KDIM / 32), 256, 0, stream>>>(x, Xpk);
  gemm_kernel<<<dim3(NDIM / 128, MDIM / 128), 256, 0, stream>>>(Wpk, Xpk, bias, y);
}

// Round 5
// 366.617 us; speedup vs baseline: 2.2009x; 1.0399x over previous
//
#include <hip/hip_runtime.h>
#include <hip/hip_bf16.h>
#include <stdint.h>

#define MDIM 4096
#define NDIM 4096
#define KDIM 4096

typedef float f32x4 __attribute__((ext_vector_type(4)));
typedef __bf16 bf16x8 __attribute__((ext_vector_type(8)));
typedef short s16x8 __attribute__((ext_vector_type(8)));

// Packed fragment-order layout for a 4096x4096 bf16 operand P[row][k]:
//   band b = row>>7, ktile t = k>>5, frag f = (row&127)>>4,
//   lane = ((k>>3)&3)*16 + (row&15), j = k&7
//   short index = ((((b*128 + t)*8 + f)*64) + lane)*8 + j
// One frag = 1KB contiguous => wave reads contiguous in global AND LDS.

__device__ __forceinline__ unsigned short f2bf(float x) {
  union { float f; unsigned u; } v; v.f = x;
  return (unsigned short)((v.u + 0x7fffu + ((v.u >> 16) & 1u)) >> 16);
}
__device__ __forceinline__ float bf2f(unsigned short b) {
  union { unsigned u; float f; } v; v.u = ((unsigned)b) << 16;
  return v.f;
}

// ---- packed-bf16 atomic add with SFINAE fallback to CAS loop ----
// Preferred: HW global_atomic_pk_add_bf16 (fire-and-forget, one mem op).
// Fallback (if this ROCm lacks the bf162 unsafeAtomicAdd overload): R4's CAS.
__device__ __forceinline__ void cas_add_bf16(unsigned short* addr2, unsigned short bits, int hi) {
  unsigned* word = (unsigned*)addr2;
  unsigned shift = hi ? 16u : 0u;
  float v = bf2f(bits);
  unsigned old = *word, assumed;
  do {
    assumed = old;
    unsigned short cur = (unsigned short)(assumed >> shift);
    unsigned short upd = f2bf(bf2f(cur) + v);
    unsigned next = (assumed & ~(0xffffu << shift)) | ((unsigned)upd << shift);
    if (next == assumed) break;
    old = atomicCAS(word, assumed, next);
  } while (old != assumed);
}

template <typename T>
__device__ __forceinline__ auto pk_add_impl(T* p, T v, int)
    -> decltype(unsafeAtomicAdd(p, v), void()) {
  unsafeAtomicAdd(p, v);
}
template <typename T>
__device__ __forceinline__ void pk_add_impl(T* p, T v, long) {
  union { T t; unsigned u; } c; c.t = v;
  unsigned short lo = (unsigned short)(c.u & 0xffffu);
  unsigned short hi16 = (unsigned short)(c.u >> 16);
  if (lo) cas_add_bf16((unsigned short*)p, lo, 0);
  if (hi16) cas_add_bf16((unsigned short*)p, hi16, 1);
}

__device__ __forceinline__ void atomic_bf16_add(unsigned short* base2, unsigned short bits, int hi) {
  __hip_bfloat162_raw raw;
  raw.x = hi ? (unsigned short)0 : bits;
  raw.y = hi ? bits : (unsigned short)0;
  __hip_bfloat162 v(raw);
  pk_add_impl((__hip_bfloat162*)base2, v, 0);
}

// ---- fused prep: blocks [0, scBlocks) scatter COO; rest pack x ----
__global__ __launch_bounds__(256) void prep_kernel(const int* __restrict__ rows,
                                                   const int* __restrict__ cols,
                                                   const float* __restrict__ vals, int nnz,
                                                   int scBlocks,
                                                   unsigned short* __restrict__ Wpk,
                                                   const float* __restrict__ x,
                                                   short* __restrict__ Xpk) {
  int b = blockIdx.x, tid = threadIdx.x;
  if (b < scBlocks) {
    // -- scatter: one fire-and-forget pk_add_bf16 per nnz --
    int i = b * 256 + tid;
    if (i >= nnz) return;
    int m = rows[i], k = cols[i];
    unsigned short bits = f2bf(vals[i]);
    size_t chunk = ((((size_t)(m >> 7) * 128 + (k >> 5)) * 8 + ((m >> 4) & 7)) * 64) +
                   (((k >> 3) & 3) * 16 + (m & 15));
    size_t idx = chunk * 8 + (k & 7);
    atomic_bf16_add(&Wpk[idx & ~(size_t)1], bits, (int)(idx & 1));
  } else {
    // -- packx: tile n=64 x k=32 -> packed bf16 (4 contiguous 1KB runs) --
    __shared__ float tile[32 * 65];
    int pb = b - scBlocks;
    int n0 = (pb & 63) * 64, k0 = (pb >> 6) * 32;
#pragma unroll
    for (int r = 0; r < 8; r++) {
      int elem = r * 256 + tid;
      int kk = elem >> 6, nn = elem & 63;
      tile[kk * 65 + nn] = x[(size_t)(k0 + kk) * NDIM + n0 + nn];
    }
    __syncthreads();
    int region = tid >> 6, lane = tid & 63;
    int kh = lane >> 4, nl = region * 16 + (lane & 15);
    s16x8 v;
#pragma unroll
    for (int j = 0; j < 8; j++) v[j] = (short)f2bf(tile[(kh * 8 + j) * 65 + nl]);
    int f = region;  // (n0 & 127) >> 4 == 0 since n0 is a multiple of 64... careful:
    f = ((n0 & 127) >> 4) + region;
    size_t chunk = (((size_t)(n0 >> 7) * 128 + (k0 >> 5)) * 8 + f) * 64 + lane;
    *(s16x8*)&Xpk[chunk * 8] = v;
  }
}

// ---- bf16 MFMA GEMM on packed operands, double-buffered LDS (unchanged R4) ----
__global__ __launch_bounds__(256) void gemm_kernel(const short* __restrict__ A,
                                                   const short* __restrict__ Bt,
                                                   const float* __restrict__ bias,
                                                   float* __restrict__ C) {
  __shared__ __align__(16) short sA[2][128 * 32];
  __shared__ __align__(16) short sB[2][128 * 32];
  int tid = threadIdx.x, lane = tid & 63, wave = tid >> 6;
  int wr = wave >> 1, wc = wave & 1;
  int m16 = lane & 15, quad = lane >> 4;
  int rowBase = blockIdx.y * 128, colBase = blockIdx.x * 128;

  f32x4 acc[4][4];
#pragma unroll
  for (int i = 0; i < 4; i++)
#pragma unroll
    for (int j = 0; j < 4; j++) acc[i][j] = f32x4{0.f, 0.f, 0.f, 0.f};

  const short* aSrc[2];
  const short* bSrc[2];
  int ldsDst[2];
#pragma unroll
  for (int s = 0; s < 2; s++) {
    int f = wave + s * 4;
    aSrc[s] = A + ((size_t)blockIdx.y * 128 * 8 + f) * 512 + lane * 8;
    bSrc[s] = Bt + ((size_t)blockIdx.x * 128 * 8 + f) * 512 + lane * 8;
    ldsDst[s] = f * 512;
  }

#pragma unroll
  for (int s = 0; s < 2; s++) {
    __builtin_amdgcn_global_load_lds(
        (const __attribute__((address_space(1))) void*)aSrc[s],
        (__attribute__((address_space(3))) void*)&sA[0][ldsDst[s]], 16, 0, 0);
    __builtin_amdgcn_global_load_lds(
        (const __attribute__((address_space(1))) void*)bSrc[s],
        (__attribute__((address_space(3))) void*)&sB[0][ldsDst[s]], 16, 0, 0);
  }

#pragma unroll 2
  for (int it = 0; it < 128; it++) {
    int buf = it & 1, nxt = buf ^ 1;
    int tnext = (it + 1) & 127;  // wrap prefetch stays in-bounds
#pragma unroll
    for (int s = 0; s < 2; s++) {
      __builtin_amdgcn_global_load_lds(
          (const __attribute__((address_space(1))) void*)(aSrc[s] + (size_t)tnext * 4096),
          (__attribute__((address_space(3))) void*)&sA[nxt][ldsDst[s]], 16, 0, 0);
      __builtin_amdgcn_global_load_lds(
          (const __attribute__((address_space(1))) void*)(bSrc[s] + (size_t)tnext * 4096),
          (__attribute__((address_space(3))) void*)&sB[nxt][ldsDst[s]], 16, 0, 0);
    }
    __builtin_amdgcn_s_waitcnt(0x0F74);  // vmcnt(4)
    __builtin_amdgcn_s_barrier();

    bf16x8 a[4], b[4];
#pragma unroll
    for (int i = 0; i < 4; i++)
      a[i] = *(const bf16x8*)&sA[buf][((wr * 4 + i) * 64 + lane) * 8];
#pragma unroll
    for (int j = 0; j < 4; j++)
      b[j] = *(const bf16x8*)&sB[buf][((wc * 4 + j) * 64 + lane) * 8];
#pragma unroll
    for (int i = 0; i < 4; i++)
#pragma unroll
      for (int j = 0; j < 4; j++)
        acc[i][j] = __builtin_amdgcn_mfma_f32_16x16x32_bf16(a[i], b[j], acc[i][j], 0, 0, 0);

    __builtin_amdgcn_s_waitcnt(0xC07F);  // lgkmcnt(0)
    __builtin_amdgcn_s_barrier();
  }
  __builtin_amdgcn_s_waitcnt(0x0F70);  // vmcnt(0): drain wrap prefetch

#pragma unroll
  for (int j = 0; j < 4; j++) {
    int col = colBase + wc * 64 + j * 16 + m16;
    float bv = bias[col];
#pragma unroll
    for (int i = 0; i < 4; i++) {
      int row0 = rowBase + wr * 64 + i * 16 + quad * 4;
      f32x4 v = acc[i][j];
#pragma unroll
      for (int r = 0; r < 4; r++) C[(size_t)(row0 + r) * NDIM + col] = v[r] + bv;
    }
  }
}

extern "C" void kernel_launch(void* const* d_in, const int* in_sizes, int n_in,
                              void* d_out, int out_size, void* d_ws, size_t ws_size,
                              hipStream_t stream) {
  const float* x = (const float*)d_in[0];
  const int* rows = (const int*)d_in[1];
  const int* cols = (const int*)d_in[2];
  const float* vals = (const float*)d_in[3];
  const float* bias = (const float*)d_in[4];
  int nnz = in_sizes[1];
  float* y = (float*)d_out;

  char* ws = (char*)d_ws;
  unsigned short* Wpk = (unsigned short*)ws;
  short* Xpk = (short*)(ws + (32u << 20));

  int scBlocks = (nnz + 255) / 256;
  int pxBlocks = (NDIM / 64) * (KDIM / 32);  // 8192

  hipMemsetAsync(Wpk, 0, (size_t)MDIM * KDIM * sizeof(short), stream);
  prep_kernel<<<scBlocks + pxBlocks, 256, 0, stream>>>(rows, cols, vals, nnz, scBlocks,
                                                       Wpk, x, Xpk);
  gemm_kernel<<<dim3(NDIM / 128, MDIM / 128), 256, 0, stream>>>((const short*)Wpk, Xpk, bias, y);
}